// Round 11
// baseline (82.599 us; speedup 1.0000x reference)
//
#include <hip/hip_runtime.h>
#include <hip/hip_bf16.h>
#include <hip/hip_fp8.h>
#include <stdint.h>

// Problem constants (fixed by reference): B=2048, D=256, Vg=2, Vt=4 (only j<2 used), T=0.2
#define TB 2048
#define TD 256

typedef long long                                         fp8x8;   // 8 fp8 = 2 VGPR
typedef __attribute__((ext_vector_type(8)))  int          int8v;   // 32 fp8 = 8 VGPR
typedef __attribute__((ext_vector_type(16))) float        f32x16;

union frag32 { fp8x8 g[4]; int8v v; };   // 4 x 8B granules = one 32x32x64 operand

#define SQRT5 2.23606797749979f   // fold sqrt(1/T)=sqrt(5) into BOTH normalized operands
#define SCALE1 0x7F               // E8M0: 2^(127-127) = 1.0

// ---------------------------------------------------------------------------
// Single fused kernel. Grid = 512 blocks x 256 thr = exactly 2 blocks/CU
// (co-residency guaranteed by __launch_bounds__(256,2): VGPR<=256, LDS 16.7KB)
// Phase A: prep (normalize+fp8-pack, 16 rows/block)  -> pq2
// grid barrier 1 (spin, all blocks)
// Phase B: MX-fp8 MFMA main (identical to R10)       -> sPart/dPart
// grid barrier 2 (arrive-only; block 0 spins)
// Phase C: block 0 final reduce                       -> out[3]
// cnt is zeroed by hipMemsetAsync before each launch -> deterministic.
// ---------------------------------------------------------------------------
__global__ __launch_bounds__(256, 2) void nnclr_fused(const float* __restrict__ proj,
                                                      const float* __restrict__ pred,
                                                      unsigned char* __restrict__ pq2,
                                                      float* __restrict__ sPart,  // [4][2048][4]
                                                      float* __restrict__ dPart,  // [4][2048][4]
                                                      unsigned int* __restrict__ cnt,
                                                      float* __restrict__ out) {
    const int bid = blockIdx.x;          // 0..511
    const int t   = threadIdx.x;         // 0..255

    __shared__ __align__(16) unsigned char ldsraw[16704];
    float (*rowbuf)[260] = (float(*)[260])ldsraw;        // [16][260]
    float* scales = (float*)(ldsraw + 16640);            // [16]

    // ================= Phase A: prep unit (grp, v, half) =================
    {
        const int grp = bid >> 3, v = (bid >> 1) & 3, half = bid & 1;
        #pragma unroll
        for (int it = 0; it < 4; ++it) {
            const int f = it * 256 + t;          // 0..1023 float4-slot
            const int m = f >> 6, q = f & 63;    // local row (0..15), float4-col
            const int b = grp * 32 + half * 16 + m;
            const float4* src = (v < 2) ? (const float4*)(proj + ((size_t)b * 2 + v) * TD)
                                        : (const float4*)(pred + ((size_t)b * 4 + (v - 2)) * TD);
            *(float4*)&rowbuf[m][q * 4] = src[q];
        }
        __syncthreads();
        // norms: 16 threads per row
        {
            const int row = t >> 4, l16 = t & 15;
            float ss = 0.f;
            #pragma unroll
            for (int n = 0; n < 16; ++n) { const float y = rowbuf[row][l16 + 16 * n]; ss += y * y; }
            ss += __shfl_xor(ss, 1, 64);
            ss += __shfl_xor(ss, 2, 64);
            ss += __shfl_xor(ss, 4, 64);
            ss += __shfl_xor(ss, 8, 64);
            if (l16 == 0) scales[row] = SQRT5 / fmaxf(sqrtf(ss), 1e-12f);
        }
        __syncthreads();
        // pack our 16 batch-cols (col = half*16+colloc), all 32 granules
        // uint index u = g*64 + col*2 + e4 (byte-identical to R10 prep layout)
        unsigned int* dst32 = (unsigned int*)(pq2 + (size_t)(v * 64 + grp) * 8192);
        #pragma unroll
        for (int it = 0; it < 4; ++it) {
            const int idx = it * 256 + t;        // 0..1023
            const int g = idx >> 5, colloc = (idx >> 1) & 15, e4 = idx & 1;
            const float sc = scales[colloc];
            unsigned int w = 0;
            #pragma unroll
            for (int i = 0; i < 4; ++i) {
                const float y = rowbuf[colloc][g * 8 + 4 * e4 + i] * sc;
                const __hip_fp8_e4m3 f8(y);
                w |= ((unsigned int)f8.__x) << (8 * i);
            }
            dst32[g * 64 + (half * 16 + colloc) * 2 + e4] = w;
        }
    }

    // ================= grid barrier 1 (all blocks spin) =================
    __syncthreads();
    if (t == 0) {
        __threadfence();                         // release phase-A stores
        atomicAdd(cnt, 1u);
        while (atomicAdd(cnt, 0u) < 512u) __builtin_amdgcn_s_sleep(16);
        __threadfence();                         // acquire remote stores
    }
    __syncthreads();

    // ================= Phase B: MX-fp8 MFMA main (== R10) =================
    {
        const int rb = bid >> 3, ch = (bid >> 1) & 3, j = bid & 1;
        const int lane = t & 63, wave = t >> 6;
        const int cl = lane & 31, hk = lane >> 5;
        const int b0 = rb * 32;

        const fp8x8* P = (const fp8x8*)pq2;
        frag32 aF0[4], aF1[4];
        #pragma unroll
        for (int kb = 0; kb < 4; ++kb) {
            #pragma unroll
            for (int q = 0; q < 4; ++q) {
                const int g = 8 * kb + 4 * hk + q;
                aF0[kb].g[q] = P[((0 * 64 + rb) * 32 + g) * 32 + cl];
                aF1[kb].g[q] = P[((1 * 64 + rb) * 32 + g) * 32 + cl];
            }
        }

        float sAcc0[16], sAcc1[16];
        #pragma unroll
        for (int r = 0; r < 16; ++r) { sAcc0[r] = 0.f; sAcc1[r] = 0.f; }
        float d0 = 0.f, d1 = 0.f;
        const int  rDiag    = (cl & 3) + 4 * (cl >> 3);
        const bool laneDiag = (((cl >> 2) & 1) == hk);

        const fp8x8* Bbase = P + (size_t)(2 + j) * 64 * 32 * 32;
        const int cg0 = ch * 16 + wave * 4;

        frag32 bf[2][4];
        #pragma unroll
        for (int kb = 0; kb < 4; ++kb)
            #pragma unroll
            for (int q = 0; q < 4; ++q)
                bf[0][kb].g[q] = Bbase[((size_t)cg0 * 32 + 8 * kb + 4 * hk + q) * 32 + cl];

        #pragma unroll
        for (int cgl = 0; cgl < 4; ++cgl) {
            const int cg = cg0 + cgl;
            if (cgl < 3) {
                #pragma unroll
                for (int kb = 0; kb < 4; ++kb)
                    #pragma unroll
                    for (int q = 0; q < 4; ++q)
                        bf[(cgl + 1) & 1][kb].g[q] =
                            Bbase[((size_t)(cg + 1) * 32 + 8 * kb + 4 * hk + q) * 32 + cl];
            }
            f32x16 acc0, acc1;
            #pragma unroll
            for (int r = 0; r < 16; ++r) { acc0[r] = 0.f; acc1[r] = 0.f; }
            #pragma unroll
            for (int kb = 0; kb < 4; ++kb) {
                acc0 = __builtin_amdgcn_mfma_scale_f32_32x32x64_f8f6f4(
                           aF0[kb].v, bf[cgl & 1][kb].v, acc0, 0, 0, 0, SCALE1, 0, SCALE1);
                acc1 = __builtin_amdgcn_mfma_scale_f32_32x32x64_f8f6f4(
                           aF1[kb].v, bf[cgl & 1][kb].v, acc1, 0, 0, 0, SCALE1, 0, SCALE1);
            }
            const bool diagCG = (cg == rb);
            #pragma unroll
            for (int r = 0; r < 16; ++r) {
                const float v0 = acc0[r], v1 = acc1[r];
                sAcc0[r] += __expf(v0 - 5.0f);
                sAcc1[r] += __expf(v1 - 5.0f);
                if (diagCG) {
                    const bool m = laneDiag && (r == rDiag);
                    d0 += m ? v0 : 0.f;
                    d1 += m ? v1 : 0.f;
                }
            }
        }

        #pragma unroll
        for (int r = 0; r < 16; ++r) {
            float s0 = sAcc0[r], s1 = sAcc1[r];
            #pragma unroll
            for (int msk = 1; msk < 32; msk <<= 1) {
                s0 += __shfl_xor(s0, msk, 64);
                s1 += __shfl_xor(s1, msk, 64);
            }
            sAcc0[r] = s0; sAcc1[r] = s1;
        }

        float* sArr = (float*)ldsraw;               // [2][4][32]
        float* dArr = (float*)(ldsraw + 1024);      // [2][4][32]
        if (cl == 0) {
            #pragma unroll
            for (int r = 0; r < 16; ++r) {
                const int rowl = (r & 3) + 8 * (r >> 2) + 4 * hk;
                sArr[(0 * 4 + wave) * 32 + rowl] = sAcc0[r];
                sArr[(1 * 4 + wave) * 32 + rowl] = sAcc1[r];
            }
        }
        if (laneDiag) { dArr[(0 * 4 + wave) * 32 + cl] = d0; dArr[(1 * 4 + wave) * 32 + cl] = d1; }
        __syncthreads();
        if (t < 64) {
            const int i = t >> 5, row = t & 31;
            float s = 0.f, d = 0.f;
            #pragma unroll
            for (int w = 0; w < 4; ++w) {
                s += sArr[(i * 4 + w) * 32 + row];
                d += dArr[(i * 4 + w) * 32 + row];
            }
            const int pair = i * 2 + j;
            const int b = b0 + row;
            sPart[((size_t)pair * TB + b) * 4 + ch] = s;
            dPart[((size_t)pair * TB + b) * 4 + ch] = d;
        }
    }

    // ================= grid barrier 2 (arrive; only block 0 spins) =================
    __syncthreads();
    if (t == 0) { __threadfence(); atomicAdd(cnt, 1u); }
    if (bid != 0) return;
    if (t == 0) {
        while (atomicAdd(cnt, 0u) < 1024u) __builtin_amdgcn_s_sleep(16);
        __threadfence();
    }
    __syncthreads();

    // ================= Phase C: block 0 final reduce =================
    {
        float acc[4] = {0.f, 0.f, 0.f, 0.f};
        #pragma unroll
        for (int k = 0; k < 32; ++k) {
            const int item = k * 256 + t;            // pair = k>>3 (static index)
            const float4 sv = ((const float4*)sPart)[item];
            const float4 dv = ((const float4*)dPart)[item];
            const float s = (sv.x + sv.y) + (sv.z + sv.w);
            const float d = (dv.x + dv.y) + (dv.z + dv.w);
            acc[k >> 3] += 5.0f + logf(s) - d;
        }
        float* red = (float*)ldsraw;                 // [4 waves][4 pairs]
        const int lane = t & 63, wave = t >> 6;
        #pragma unroll
        for (int p = 0; p < 4; ++p) {
            #pragma unroll
            for (int m = 1; m < 64; m <<= 1) acc[p] += __shfl_xor(acc[p], m, 64);
        }
        if (lane == 0) {
            #pragma unroll
            for (int p = 0; p < 4; ++p) red[wave * 4 + p] = acc[p];
        }
        __syncthreads();
        if (t == 0) {
            float L[4];
            #pragma unroll
            for (int p = 0; p < 4; ++p)
                L[p] = (red[0 * 4 + p] + red[1 * 4 + p] + red[2 * 4 + p] + red[3 * 4 + p]) / (float)TB;
            const float gs = L[1] + L[2];                 // L[0][1] + L[1][0]
            const float ls = L[0] + L[1] + L[2] + L[3];   // all four (Vl==Vg==2)
            out[0] = (gs + ls) / 6.0f;        // total
            out[1] = gs * 0.5f;               // global_loss
            out[2] = ls * 0.25f;              // local_loss
        }
    }
}

extern "C" void kernel_launch(void* const* d_in, const int* in_sizes, int n_in,
                              void* d_out, int out_size, void* d_ws, size_t ws_size,
                              hipStream_t stream) {
    const float* projected = (const float*)d_in[0];   // [2048][2][256] f32
    const float* predicted = (const float*)d_in[1];   // [2048][4][256] f32

    unsigned char* pq2 = (unsigned char*)d_ws;                          // 2 MB fp8, fragment-ordered
    float* sPart = (float*)((char*)d_ws + 4u * 1024u * 1024u);          // 128 KB
    float* dPart = sPart + (size_t)4 * TB * 4;                          // 128 KB
    unsigned int* cnt = (unsigned int*)((char*)d_ws + 4u * 1024u * 1024u + 256u * 1024u);
    float* out = (float*)d_out;

    hipMemsetAsync(cnt, 0, 4, stream);               // reset barrier counter (graph-capturable)
    nnclr_fused<<<512, 256, 0, stream>>>(projected, predicted, pq2, sPart, dPart, cnt, out);
}